// Round 1
// baseline (1561.764 us; speedup 1.0000x reference)
//
#include <hip/hip_runtime.h>

#define N_NODES 100000
#define N_EDGES 1600000
#define F 128

// ---------------------------------------------------------------------------
// Kernel 1: edge scatter. One wave (64 lanes) per edge; each lane handles a
// float2 (128 floats per edge). agg[dst] += feat[src] / out_norm[src].
// agg == d_out (memset to 0 first). unsafeAtomicAdd -> global_atomic_add_f32.
// ---------------------------------------------------------------------------
__global__ __launch_bounds__(256) void scatter_kernel(
    const float* __restrict__ feat, const float* __restrict__ out_norm,
    const int* __restrict__ src, const int* __restrict__ dst,
    float* __restrict__ agg)
{
    const int wave = threadIdx.x >> 6;
    const int lane = threadIdx.x & 63;
    const int e = blockIdx.x * 4 + wave;   // grid = E/4 exactly, no tail
    const int s = src[e];
    const int d = dst[e];
    const float rn = 1.0f / out_norm[s];
    const float2 v = ((const float2*)(feat + (size_t)s * F))[lane];
    float* ap = agg + (size_t)d * F + lane * 2;
    unsafeAtomicAdd(ap,     v.x * rn);
    unsafeAtomicAdd(ap + 1, v.y * rn);
}

// ---------------------------------------------------------------------------
// Kernel 2: in-place row transform. out_row = (row / in_norm) @ W^T + b.
// W^T staged in LDS as Wt[k*128 + j] (64 KB, conflict-free inner reads:
// lane j reads Wt[k*128+j] -> 32 banks x 2 lanes = free).
// Each wave processes 4 rows; lane computes outputs j=lane and j=lane+64.
// Row reads are wave-uniform-address broadcasts (L1-served).
// In-place is safe: a wave reads its entire rows (loop over all k) before
// writing them, and no other wave touches those rows.
// ---------------------------------------------------------------------------
__global__ __launch_bounds__(256) void transform_kernel(
    float* __restrict__ out, const float* __restrict__ in_norm,
    const float* __restrict__ W, const float* __restrict__ bias)
{
    __shared__ float Wt[F * F];   // exactly 64 KB
    const int t = threadIdx.x;
    // Cooperative transposed stage: Wt[k*F + j] = W[j*F + k].
    #pragma unroll
    for (int i = 0; i < (F * F) / 256; ++i) {
        int idx = t + i * 256;
        int j = idx >> 7;
        int k = idx & (F - 1);
        Wt[k * F + j] = W[idx];
    }
    __syncthreads();

    const int wave = t >> 6, lane = t & 63;
    const float b0 = bias[lane];
    const float b1 = bias[lane + 64];
    const int ngroups = N_NODES / 16;   // 6250, exact (16 rows per group)

    for (int g = blockIdx.x; g < ngroups; g += gridDim.x) {
        const int r = g * 16 + wave * 4;
        const float* a0 = out + (size_t)r * F;
        const float* a1 = a0 + F;
        const float* a2 = a0 + 2 * F;
        const float* a3 = a0 + 3 * F;
        float acc00 = 0.f, acc01 = 0.f, acc10 = 0.f, acc11 = 0.f;
        float acc20 = 0.f, acc21 = 0.f, acc30 = 0.f, acc31 = 0.f;
        #pragma unroll 4
        for (int k = 0; k < F; ++k) {
            const float w0 = Wt[k * F + lane];
            const float w1 = Wt[k * F + 64 + lane];
            const float x0 = a0[k];
            const float x1 = a1[k];
            const float x2 = a2[k];
            const float x3 = a3[k];
            acc00 = fmaf(x0, w0, acc00); acc01 = fmaf(x0, w1, acc01);
            acc10 = fmaf(x1, w0, acc10); acc11 = fmaf(x1, w1, acc11);
            acc20 = fmaf(x2, w0, acc20); acc21 = fmaf(x2, w1, acc21);
            acc30 = fmaf(x3, w0, acc30); acc31 = fmaf(x3, w1, acc31);
        }
        const float i0 = 1.0f / in_norm[r + 0];
        const float i1 = 1.0f / in_norm[r + 1];
        const float i2 = 1.0f / in_norm[r + 2];
        const float i3 = 1.0f / in_norm[r + 3];
        out[(size_t)(r + 0) * F + lane]      = acc00 * i0 + b0;
        out[(size_t)(r + 0) * F + 64 + lane] = acc01 * i0 + b1;
        out[(size_t)(r + 1) * F + lane]      = acc10 * i1 + b0;
        out[(size_t)(r + 1) * F + 64 + lane] = acc11 * i1 + b1;
        out[(size_t)(r + 2) * F + lane]      = acc20 * i2 + b0;
        out[(size_t)(r + 2) * F + 64 + lane] = acc21 * i2 + b1;
        out[(size_t)(r + 3) * F + lane]      = acc30 * i3 + b0;
        out[(size_t)(r + 3) * F + 64 + lane] = acc31 * i3 + b1;
    }
}

extern "C" void kernel_launch(void* const* d_in, const int* in_sizes, int n_in,
                              void* d_out, int out_size, void* d_ws, size_t ws_size,
                              hipStream_t stream) {
    const float* feat     = (const float*)d_in[0];
    const float* in_norm  = (const float*)d_in[1];
    const float* out_norm = (const float*)d_in[2];
    const int*   src      = (const int*)d_in[3];
    const int*   dst      = (const int*)d_in[4];
    const float* W        = (const float*)d_in[5];
    const float* b        = (const float*)d_in[6];
    float* out = (float*)d_out;

    // agg accumulates directly in d_out; zero it first (graph-capturable).
    hipMemsetAsync(out, 0, (size_t)N_NODES * F * sizeof(float), stream);

    scatter_kernel<<<N_EDGES / 4, 256, 0, stream>>>(feat, out_norm, src, dst, out);

    transform_kernel<<<2048, 256, 0, stream>>>(out, in_norm, W, b);
}

// Round 2
// 585.080 us; speedup vs baseline: 2.6693x; 2.6693x over previous
//
#include <hip/hip_runtime.h>

#define N_NODES 100000
#define N_EDGES 1600000
#define F 128
#define NPAD 100352  // N_NODES padded to multiple of 256

// ---------------- workspace layout (bytes) ----------------
// cnt      : NPAD ints   @ 0
// offs     : NPAD ints   @ 401408
// rno      : NPAD floats @ 802816
// partials : 512 ints    @ 1204224
// ssrc     : N_EDGES ints@ 1206272
// total 7,606,272 bytes
#define WS_NEEDED 7606272

// ---------------------------------------------------------------------------
// CSR build: prep (zero counts + reciprocal out_norm), histogram of dst,
// 3-phase exclusive scan, counting-sort fill of src ids grouped by dst.
// All atomics are int adds on L2-resident arrays (cheap), no fp32 atomics.
// ---------------------------------------------------------------------------
__global__ __launch_bounds__(256) void prep_kernel(
    const float* __restrict__ out_norm, float* __restrict__ rno,
    int* __restrict__ cnt)
{
    int i = blockIdx.x * 256 + threadIdx.x;
    if (i < N_NODES) { rno[i] = 1.0f / out_norm[i]; cnt[i] = 0; }
}

__global__ __launch_bounds__(256) void hist_kernel(
    const int* __restrict__ dst, int* __restrict__ cnt)
{
    int e = blockIdx.x * 256 + threadIdx.x;   // grid = E/256 exact
    atomicAdd(&cnt[dst[e]], 1);
}

__global__ __launch_bounds__(256) void scanA_kernel(
    const int* __restrict__ cnt, int* __restrict__ offs,
    int* __restrict__ partials)
{
    __shared__ int sm[256];
    int t = threadIdx.x;
    int i = blockIdx.x * 256 + t;
    int v = (i < N_NODES) ? cnt[i] : 0;
    sm[t] = v;
    __syncthreads();
    for (int off = 1; off < 256; off <<= 1) {
        int x = (t >= off) ? sm[t - off] : 0;
        __syncthreads();
        sm[t] += x;
        __syncthreads();
    }
    if (i < N_NODES) offs[i] = sm[t] - v;      // exclusive within block
    if (t == 255) partials[blockIdx.x] = sm[255];
}

__global__ __launch_bounds__(512) void scanB_kernel(int* __restrict__ partials, int nb)
{
    __shared__ int sm[512];
    int t = threadIdx.x;
    int v = (t < nb) ? partials[t] : 0;
    sm[t] = v;
    __syncthreads();
    for (int off = 1; off < 512; off <<= 1) {
        int x = (t >= off) ? sm[t - off] : 0;
        __syncthreads();
        sm[t] += x;
        __syncthreads();
    }
    if (t < nb) partials[t] = sm[t] - v;       // exclusive
}

__global__ __launch_bounds__(256) void scanC_kernel(
    int* __restrict__ offs, const int* __restrict__ partials)
{
    int i = blockIdx.x * 256 + threadIdx.x;
    if (i < N_NODES) offs[i] += partials[blockIdx.x];
}

__global__ __launch_bounds__(256) void fill_kernel(
    const int* __restrict__ src, const int* __restrict__ dst,
    int* __restrict__ offs, int* __restrict__ ssrc)
{
    int e = blockIdx.x * 256 + threadIdx.x;   // grid = E/256 exact
    int d = dst[e];
    int pos = atomicAdd(&offs[d], 1);         // offs becomes end[] after fill
    ssrc[pos] = src[e];
}

// ---------------------------------------------------------------------------
// Gather aggregation: one wave per node; lane holds a float2 (128 floats/row).
// After fill, offs[i] == end[i]; start[i] == offs[i-1] (end of previous).
// Each agg row written exactly once -> no atomics, WRITE_SIZE ~= 51 MB.
// feat (51.2 MB) is L3-resident -> gather reads served from cache.
// ---------------------------------------------------------------------------
__global__ __launch_bounds__(256) void gather_kernel(
    const float* __restrict__ feat, const float* __restrict__ rno,
    const int* __restrict__ offs, const int* __restrict__ ssrc,
    float* __restrict__ agg)
{
    const int wave = threadIdx.x >> 6, lane = threadIdx.x & 63;
    const int i = blockIdx.x * 4 + wave;      // grid = N/4 exact
    const int start = (i == 0) ? 0 : offs[i - 1];
    const int end = offs[i];
    float ax = 0.f, ay = 0.f;
    int e = start;
    for (; e + 1 < end; e += 2) {
        int s0 = ssrc[e], s1 = ssrc[e + 1];
        float r0 = rno[s0], r1 = rno[s1];
        float2 v0 = ((const float2*)feat)[(size_t)s0 * 64 + lane];
        float2 v1 = ((const float2*)feat)[(size_t)s1 * 64 + lane];
        ax = fmaf(v0.x, r0, ax); ay = fmaf(v0.y, r0, ay);
        ax = fmaf(v1.x, r1, ax); ay = fmaf(v1.y, r1, ay);
    }
    if (e < end) {
        int s = ssrc[e];
        float r = rno[s];
        float2 v = ((const float2*)feat)[(size_t)s * 64 + lane];
        ax = fmaf(v.x, r, ax); ay = fmaf(v.y, r, ay);
    }
    float2 o; o.x = ax; o.y = ay;
    ((float2*)agg)[(size_t)i * 64 + lane] = o;
}

// ---------------------------------------------------------------------------
// In-place row transform: out_row = (row / in_norm) @ W^T + b.
// W^T in LDS (64 KB); x rows loaded as uniform float4 (1 load per 4 k).
// ---------------------------------------------------------------------------
__global__ __launch_bounds__(256) void transform_kernel(
    float* __restrict__ out, const float* __restrict__ in_norm,
    const float* __restrict__ W, const float* __restrict__ bias)
{
    __shared__ float Wt[F * F];   // 64 KB
    const int t = threadIdx.x;
    #pragma unroll
    for (int i = 0; i < (F * F) / 256; ++i) {
        int idx = t + i * 256;
        int j = idx >> 7;
        int k = idx & (F - 1);
        Wt[k * F + j] = W[idx];
    }
    __syncthreads();

    const int wave = t >> 6, lane = t & 63;
    const float b0 = bias[lane];
    const float b1 = bias[lane + 64];
    const int ngroups = N_NODES / 16;   // 6250 exact

    for (int g = blockIdx.x; g < ngroups; g += gridDim.x) {
        const int r = g * 16 + wave * 4;
        const float4* a0 = (const float4*)(out + (size_t)r * F);
        const float4* a1 = a0 + F / 4;
        const float4* a2 = a0 + 2 * (F / 4);
        const float4* a3 = a0 + 3 * (F / 4);
        float acc00 = 0.f, acc01 = 0.f, acc10 = 0.f, acc11 = 0.f;
        float acc20 = 0.f, acc21 = 0.f, acc30 = 0.f, acc31 = 0.f;
        for (int k4 = 0; k4 < F / 4; ++k4) {
            const float4 x0 = a0[k4];
            const float4 x1 = a1[k4];
            const float4 x2 = a2[k4];
            const float4 x3 = a3[k4];
            const float xs0[4] = {x0.x, x0.y, x0.z, x0.w};
            const float xs1[4] = {x1.x, x1.y, x1.z, x1.w};
            const float xs2[4] = {x2.x, x2.y, x2.z, x2.w};
            const float xs3[4] = {x3.x, x3.y, x3.z, x3.w};
            #pragma unroll
            for (int kk = 0; kk < 4; ++kk) {
                const int k = k4 * 4 + kk;
                const float w0 = Wt[k * F + lane];
                const float w1 = Wt[k * F + 64 + lane];
                acc00 = fmaf(xs0[kk], w0, acc00); acc01 = fmaf(xs0[kk], w1, acc01);
                acc10 = fmaf(xs1[kk], w0, acc10); acc11 = fmaf(xs1[kk], w1, acc11);
                acc20 = fmaf(xs2[kk], w0, acc20); acc21 = fmaf(xs2[kk], w1, acc21);
                acc30 = fmaf(xs3[kk], w0, acc30); acc31 = fmaf(xs3[kk], w1, acc31);
            }
        }
        const float i0 = 1.0f / in_norm[r + 0];
        const float i1 = 1.0f / in_norm[r + 1];
        const float i2 = 1.0f / in_norm[r + 2];
        const float i3 = 1.0f / in_norm[r + 3];
        out[(size_t)(r + 0) * F + lane]      = acc00 * i0 + b0;
        out[(size_t)(r + 0) * F + 64 + lane] = acc01 * i0 + b1;
        out[(size_t)(r + 1) * F + lane]      = acc10 * i1 + b0;
        out[(size_t)(r + 1) * F + 64 + lane] = acc11 * i1 + b1;
        out[(size_t)(r + 2) * F + lane]      = acc20 * i2 + b0;
        out[(size_t)(r + 2) * F + 64 + lane] = acc21 * i2 + b1;
        out[(size_t)(r + 3) * F + lane]      = acc30 * i3 + b0;
        out[(size_t)(r + 3) * F + 64 + lane] = acc31 * i3 + b1;
    }
}

// ---------------------------------------------------------------------------
// Fallback (ws too small): proven R1 atomic-scatter path.
// ---------------------------------------------------------------------------
__global__ __launch_bounds__(256) void scatter_kernel(
    const float* __restrict__ feat, const float* __restrict__ out_norm,
    const int* __restrict__ src, const int* __restrict__ dst,
    float* __restrict__ agg)
{
    const int wave = threadIdx.x >> 6;
    const int lane = threadIdx.x & 63;
    const int e = blockIdx.x * 4 + wave;
    const int s = src[e];
    const int d = dst[e];
    const float rn = 1.0f / out_norm[s];
    const float2 v = ((const float2*)(feat + (size_t)s * F))[lane];
    float* ap = agg + (size_t)d * F + lane * 2;
    unsafeAtomicAdd(ap,     v.x * rn);
    unsafeAtomicAdd(ap + 1, v.y * rn);
}

extern "C" void kernel_launch(void* const* d_in, const int* in_sizes, int n_in,
                              void* d_out, int out_size, void* d_ws, size_t ws_size,
                              hipStream_t stream) {
    const float* feat     = (const float*)d_in[0];
    const float* in_norm  = (const float*)d_in[1];
    const float* out_norm = (const float*)d_in[2];
    const int*   src      = (const int*)d_in[3];
    const int*   dst      = (const int*)d_in[4];
    const float* W        = (const float*)d_in[5];
    const float* b        = (const float*)d_in[6];
    float* out = (float*)d_out;

    if (ws_size >= (size_t)WS_NEEDED) {
        char* w = (char*)d_ws;
        int*   cnt      = (int*)(w + 0);
        int*   offs     = (int*)(w + 401408);
        float* rno      = (float*)(w + 802816);
        int*   partials = (int*)(w + 1204224);
        int*   ssrc     = (int*)(w + 1206272);
        const int nb = (N_NODES + 255) / 256;   // 391

        prep_kernel<<<nb, 256, 0, stream>>>(out_norm, rno, cnt);
        hist_kernel<<<N_EDGES / 256, 256, 0, stream>>>(dst, cnt);
        scanA_kernel<<<nb, 256, 0, stream>>>(cnt, offs, partials);
        scanB_kernel<<<1, 512, 0, stream>>>(partials, nb);
        scanC_kernel<<<nb, 256, 0, stream>>>(offs, partials);
        fill_kernel<<<N_EDGES / 256, 256, 0, stream>>>(src, dst, offs, ssrc);
        gather_kernel<<<N_NODES / 4, 256, 0, stream>>>(feat, rno, offs, ssrc, out);
        transform_kernel<<<2048, 256, 0, stream>>>(out, in_norm, W, b);
    } else {
        hipMemsetAsync(out, 0, (size_t)N_NODES * F * sizeof(float), stream);
        scatter_kernel<<<N_EDGES / 4, 256, 0, stream>>>(feat, out_norm, src, dst, out);
        transform_kernel<<<2048, 256, 0, stream>>>(out, in_norm, W, b);
    }
}

// Round 3
// 397.184 us; speedup vs baseline: 3.9321x; 1.4731x over previous
//
#include <hip/hip_runtime.h>

#define N_NODES 100000
#define N_EDGES 1600000
#define F 128
#define NPAD 100352
#define NBLK 391          // ceil(N/256)

// ---------------- workspace layout, fast path (bytes) ----------------
// cnt      : NPAD ints    @ 0
// offs     : NPAD ints    @ 401408
// partials : 512 ints     @ 802816
// ssrc     : E ints       @ 804864
// h (bf16) : N*128 ushort @ 7204864   (h = feat/out_norm, rno folded in)
// total 32,804,864
#define WS_FULL 32804864
// fallback (R2) layout needs 7,606,272 (cnt/offs/rno/partials/ssrc)
#define WS_R2 7606272

typedef __attribute__((ext_vector_type(8))) short short8;
typedef __attribute__((ext_vector_type(4))) float f32x4;

// RNE float -> bf16 (bit-exact with hardware cvt for normal values)
__device__ __forceinline__ unsigned short f2bf(float f) {
    unsigned u = __float_as_uint(f);
    return (unsigned short)((u + 0x7fffu + ((u >> 16) & 1u)) >> 16);
}

// ---------------------------------------------------------------------------
// prep: h[i][j] = bf16(feat[i][j] / out_norm[i]); also zero cnt.
// One thread per float4 (3.2M threads).
// ---------------------------------------------------------------------------
__global__ __launch_bounds__(256) void prep_h_kernel(
    const float* __restrict__ feat, const float* __restrict__ out_norm,
    unsigned short* __restrict__ h, int* __restrict__ cnt)
{
    int q = blockIdx.x * 256 + threadIdx.x;      // float4 index, grid exact
    int row = q >> 5;                            // 32 float4 per row
    float r = 1.0f / out_norm[row];
    float4 v = ((const float4*)feat)[q];
    ushort4 o;
    o.x = f2bf(v.x * r); o.y = f2bf(v.y * r);
    o.z = f2bf(v.z * r); o.w = f2bf(v.w * r);
    ((ushort4*)h)[q] = o;
    if (q < N_NODES) cnt[q] = 0;
}

// ---------------------------------------------------------------------------
// CSR build: histogram of dst, 3-phase exclusive scan, counting-sort fill.
// ---------------------------------------------------------------------------
__global__ __launch_bounds__(256) void hist_kernel(
    const int* __restrict__ dst, int* __restrict__ cnt)
{
    int e = blockIdx.x * 256 + threadIdx.x;
    atomicAdd(&cnt[dst[e]], 1);
}

__global__ __launch_bounds__(256) void scanA_kernel(
    const int* __restrict__ cnt, int* __restrict__ offs,
    int* __restrict__ partials)
{
    __shared__ int sm[256];
    int t = threadIdx.x;
    int i = blockIdx.x * 256 + t;
    int v = (i < N_NODES) ? cnt[i] : 0;
    sm[t] = v;
    __syncthreads();
    for (int off = 1; off < 256; off <<= 1) {
        int x = (t >= off) ? sm[t - off] : 0;
        __syncthreads();
        sm[t] += x;
        __syncthreads();
    }
    if (i < N_NODES) offs[i] = sm[t] - v;
    if (t == 255) partials[blockIdx.x] = sm[255];
}

__global__ __launch_bounds__(512) void scanB_kernel(int* __restrict__ partials, int nb)
{
    __shared__ int sm[512];
    int t = threadIdx.x;
    int v = (t < nb) ? partials[t] : 0;
    sm[t] = v;
    __syncthreads();
    for (int off = 1; off < 512; off <<= 1) {
        int x = (t >= off) ? sm[t - off] : 0;
        __syncthreads();
        sm[t] += x;
        __syncthreads();
    }
    if (t < nb) partials[t] = sm[t] - v;
}

__global__ __launch_bounds__(256) void scanC_kernel(
    int* __restrict__ offs, const int* __restrict__ partials)
{
    int i = blockIdx.x * 256 + threadIdx.x;
    if (i < N_NODES) offs[i] += partials[blockIdx.x];
}

__global__ __launch_bounds__(256) void fill_kernel(
    const int* __restrict__ src, const int* __restrict__ dst,
    int* __restrict__ offs, int* __restrict__ ssrc)
{
    int e = blockIdx.x * 256 + threadIdx.x;
    int d = dst[e];
    int pos = atomicAdd(&offs[d], 1);
    ssrc[pos] = src[e];
}

// ---------------------------------------------------------------------------
// Gather from bf16 h (rno pre-applied): pure summation. One wave per node,
// lane reads one uint (2 bf16) per incident row -> 256 B per row load.
// agg (fp32) written exactly once -> no atomics.
// ---------------------------------------------------------------------------
__global__ __launch_bounds__(256) void gather_bf16_kernel(
    const unsigned short* __restrict__ h, const int* __restrict__ offs,
    const int* __restrict__ ssrc, float* __restrict__ agg)
{
    const int wave = threadIdx.x >> 6, lane = threadIdx.x & 63;
    const int i = blockIdx.x * 4 + wave;      // grid = N/4 exact
    const int start = (i == 0) ? 0 : offs[i - 1];
    const int end = offs[i];
    const unsigned* hp = (const unsigned*)h;
    float ax = 0.f, ay = 0.f;
    int e = start;
    for (; e + 3 < end; e += 4) {
        unsigned u0 = hp[(size_t)ssrc[e]     * 64 + lane];
        unsigned u1 = hp[(size_t)ssrc[e + 1] * 64 + lane];
        unsigned u2 = hp[(size_t)ssrc[e + 2] * 64 + lane];
        unsigned u3 = hp[(size_t)ssrc[e + 3] * 64 + lane];
        ax += __uint_as_float(u0 << 16) + __uint_as_float(u1 << 16)
            + __uint_as_float(u2 << 16) + __uint_as_float(u3 << 16);
        ay += __uint_as_float(u0 & 0xffff0000u) + __uint_as_float(u1 & 0xffff0000u)
            + __uint_as_float(u2 & 0xffff0000u) + __uint_as_float(u3 & 0xffff0000u);
    }
    for (; e < end; ++e) {
        unsigned u = hp[(size_t)ssrc[e] * 64 + lane];
        ax += __uint_as_float(u << 16);
        ay += __uint_as_float(u & 0xffff0000u);
    }
    float2 o; o.x = ax; o.y = ay;
    ((float2*)agg)[(size_t)i * 64 + lane] = o;
}

// ---------------------------------------------------------------------------
// MFMA transform: out = (agg/in_norm) @ W^T + b, in-place on d_out.
// W staged bf16 in LDS (32 KB), chunk-XOR swizzle kills bank conflicts.
// Per wave: 16 rows x 128 cols = 8 col-tiles x 4 k-steps of 16x16x32 MFMA.
// A-frag: lane holds A[m=lane&15][k=(lane>>4)*8 + j] (+32 per k-step),
// converted from fp32 agg with 1/in_norm folded in.
// B-frag: lane holds B[k][n=lane&15] = W[n][k], 8 contiguous k -> one
// ds_read_b128 from the swizzled LDS image. C/D: col=lane&15,
// row=(lane>>4)*4+reg (verified layout, m89).
// In-place safe: wave fully reads its 16 rows before storing them.
// ---------------------------------------------------------------------------
__global__ __launch_bounds__(256) void transform_mfma_kernel(
    float* __restrict__ out, const float* __restrict__ in_norm,
    const float* __restrict__ W, const float* __restrict__ bias)
{
    __shared__ short Wb[F * F];   // 32 KB bf16
    const int t = threadIdx.x;
    // Stage W -> bf16 LDS. Chunk c covers W[n][kc*8 .. kc*8+8).
    // Stored at row n, chunk position (kc ^ (n & 15)).
    #pragma unroll
    for (int i = 0; i < 8; ++i) {
        int c = t + i * 256;
        int n = c >> 4, kc = c & 15;
        const float4* wp = (const float4*)(W + n * F + kc * 8);
        float4 w0 = wp[0], w1 = wp[1];
        short8 v;
        v[0] = (short)f2bf(w0.x); v[1] = (short)f2bf(w0.y);
        v[2] = (short)f2bf(w0.z); v[3] = (short)f2bf(w0.w);
        v[4] = (short)f2bf(w1.x); v[5] = (short)f2bf(w1.y);
        v[6] = (short)f2bf(w1.z); v[7] = (short)f2bf(w1.w);
        *(short8*)&Wb[n * F + ((kc ^ (n & 15)) * 8)] = v;
    }
    __syncthreads();

    const int wave = t >> 6, lane = t & 63;
    const int wblk = blockIdx.x * 4 + wave;   // 16-row block index
    if (wblk >= N_NODES / 16) return;         // 6250 blocks of 16 rows, exact
    const int r0 = wblk * 16;
    const int m = lane & 15, q = lane >> 4;
    const int arow_i = r0 + m;
    const float rin = 1.0f / in_norm[arow_i];
    const float4* arow = (const float4*)(out + (size_t)arow_i * F);

    // A fragments for the 4 k-steps (reads complete before any store).
    short8 afrag[4];
    #pragma unroll
    for (int s = 0; s < 4; ++s) {
        int k0 = s * 32 + q * 8;
        float4 x0 = arow[k0 >> 2];
        float4 x1 = arow[(k0 >> 2) + 1];
        short8 a;
        a[0] = (short)f2bf(x0.x * rin); a[1] = (short)f2bf(x0.y * rin);
        a[2] = (short)f2bf(x0.z * rin); a[3] = (short)f2bf(x0.w * rin);
        a[4] = (short)f2bf(x1.x * rin); a[5] = (short)f2bf(x1.y * rin);
        a[6] = (short)f2bf(x1.z * rin); a[7] = (short)f2bf(x1.w * rin);
        afrag[s] = a;
    }

    f32x4 acc[8];
    #pragma unroll
    for (int c = 0; c < 8; ++c) { f32x4 z = {0.f, 0.f, 0.f, 0.f}; acc[c] = z; }

    #pragma unroll
    for (int s = 0; s < 4; ++s) {
        const int kc = s * 4 + q;
        #pragma unroll
        for (int c = 0; c < 8; ++c) {
            const int n = c * 16 + m;
            short8 bfrag = *(const short8*)&Wb[n * F + ((kc ^ m) * 8)];
            acc[c] = __builtin_amdgcn_mfma_f32_16x16x32_bf16(
                afrag[s], bfrag, acc[c], 0, 0, 0);
        }
    }

    #pragma unroll
    for (int c = 0; c < 8; ++c) {
        const float bc = bias[c * 16 + m];
        #pragma unroll
        for (int r = 0; r < 4; ++r) {
            out[(size_t)(r0 + q * 4 + r) * F + c * 16 + m] = acc[c][r] + bc;
        }
    }
}

// ---------------------------------------------------------------------------
// Fallback kernels (R2/R1 proven paths)
// ---------------------------------------------------------------------------
__global__ __launch_bounds__(256) void prep_kernel(
    const float* __restrict__ out_norm, float* __restrict__ rno,
    int* __restrict__ cnt)
{
    int i = blockIdx.x * 256 + threadIdx.x;
    if (i < N_NODES) { rno[i] = 1.0f / out_norm[i]; cnt[i] = 0; }
}

__global__ __launch_bounds__(256) void gather_kernel(
    const float* __restrict__ feat, const float* __restrict__ rno,
    const int* __restrict__ offs, const int* __restrict__ ssrc,
    float* __restrict__ agg)
{
    const int wave = threadIdx.x >> 6, lane = threadIdx.x & 63;
    const int i = blockIdx.x * 4 + wave;
    const int start = (i == 0) ? 0 : offs[i - 1];
    const int end = offs[i];
    float ax = 0.f, ay = 0.f;
    int e = start;
    for (; e + 1 < end; e += 2) {
        int s0 = ssrc[e], s1 = ssrc[e + 1];
        float r0 = rno[s0], r1 = rno[s1];
        float2 v0 = ((const float2*)feat)[(size_t)s0 * 64 + lane];
        float2 v1 = ((const float2*)feat)[(size_t)s1 * 64 + lane];
        ax = fmaf(v0.x, r0, ax); ay = fmaf(v0.y, r0, ay);
        ax = fmaf(v1.x, r1, ax); ay = fmaf(v1.y, r1, ay);
    }
    if (e < end) {
        int s = ssrc[e];
        float r = rno[s];
        float2 v = ((const float2*)feat)[(size_t)s * 64 + lane];
        ax = fmaf(v.x, r, ax); ay = fmaf(v.y, r, ay);
    }
    float2 o; o.x = ax; o.y = ay;
    ((float2*)agg)[(size_t)i * 64 + lane] = o;
}

__global__ __launch_bounds__(256) void scatter_kernel(
    const float* __restrict__ feat, const float* __restrict__ out_norm,
    const int* __restrict__ src, const int* __restrict__ dst,
    float* __restrict__ agg)
{
    const int wave = threadIdx.x >> 6;
    const int lane = threadIdx.x & 63;
    const int e = blockIdx.x * 4 + wave;
    const int s = src[e];
    const int d = dst[e];
    const float rn = 1.0f / out_norm[s];
    const float2 v = ((const float2*)(feat + (size_t)s * F))[lane];
    float* ap = agg + (size_t)d * F + lane * 2;
    unsafeAtomicAdd(ap,     v.x * rn);
    unsafeAtomicAdd(ap + 1, v.y * rn);
}

__global__ __launch_bounds__(256) void transform_kernel(
    float* __restrict__ out, const float* __restrict__ in_norm,
    const float* __restrict__ W, const float* __restrict__ bias)
{
    __shared__ float Wt[F * F];
    const int t = threadIdx.x;
    #pragma unroll
    for (int i = 0; i < (F * F) / 256; ++i) {
        int idx = t + i * 256;
        int j = idx >> 7;
        int k = idx & (F - 1);
        Wt[k * F + j] = W[idx];
    }
    __syncthreads();
    const int wave = t >> 6, lane = t & 63;
    const float b0 = bias[lane];
    const float b1 = bias[lane + 64];
    const int ngroups = N_NODES / 16;
    for (int g = blockIdx.x; g < ngroups; g += gridDim.x) {
        const int r = g * 16 + wave * 4;
        const float4* a0 = (const float4*)(out + (size_t)r * F);
        const float4* a1 = a0 + F / 4;
        const float4* a2 = a0 + 2 * (F / 4);
        const float4* a3 = a0 + 3 * (F / 4);
        float acc00 = 0.f, acc01 = 0.f, acc10 = 0.f, acc11 = 0.f;
        float acc20 = 0.f, acc21 = 0.f, acc30 = 0.f, acc31 = 0.f;
        for (int k4 = 0; k4 < F / 4; ++k4) {
            const float4 x0 = a0[k4]; const float4 x1 = a1[k4];
            const float4 x2 = a2[k4]; const float4 x3 = a3[k4];
            const float xs0[4] = {x0.x, x0.y, x0.z, x0.w};
            const float xs1[4] = {x1.x, x1.y, x1.z, x1.w};
            const float xs2[4] = {x2.x, x2.y, x2.z, x2.w};
            const float xs3[4] = {x3.x, x3.y, x3.z, x3.w};
            #pragma unroll
            for (int kk = 0; kk < 4; ++kk) {
                const int k = k4 * 4 + kk;
                const float w0 = Wt[k * F + lane];
                const float w1 = Wt[k * F + 64 + lane];
                acc00 = fmaf(xs0[kk], w0, acc00); acc01 = fmaf(xs0[kk], w1, acc01);
                acc10 = fmaf(xs1[kk], w0, acc10); acc11 = fmaf(xs1[kk], w1, acc11);
                acc20 = fmaf(xs2[kk], w0, acc20); acc21 = fmaf(xs2[kk], w1, acc21);
                acc30 = fmaf(xs3[kk], w0, acc30); acc31 = fmaf(xs3[kk], w1, acc31);
            }
        }
        const float i0 = 1.0f / in_norm[r + 0];
        const float i1 = 1.0f / in_norm[r + 1];
        const float i2 = 1.0f / in_norm[r + 2];
        const float i3 = 1.0f / in_norm[r + 3];
        out[(size_t)(r + 0) * F + lane]      = acc00 * i0 + b0;
        out[(size_t)(r + 0) * F + 64 + lane] = acc01 * i0 + b1;
        out[(size_t)(r + 1) * F + lane]      = acc10 * i1 + b0;
        out[(size_t)(r + 1) * F + 64 + lane] = acc11 * i1 + b1;
        out[(size_t)(r + 2) * F + lane]      = acc20 * i2 + b0;
        out[(size_t)(r + 2) * F + 64 + lane] = acc21 * i2 + b1;
        out[(size_t)(r + 3) * F + lane]      = acc30 * i3 + b0;
        out[(size_t)(r + 3) * F + 64 + lane] = acc31 * i3 + b1;
    }
}

extern "C" void kernel_launch(void* const* d_in, const int* in_sizes, int n_in,
                              void* d_out, int out_size, void* d_ws, size_t ws_size,
                              hipStream_t stream) {
    const float* feat     = (const float*)d_in[0];
    const float* in_norm  = (const float*)d_in[1];
    const float* out_norm = (const float*)d_in[2];
    const int*   src      = (const int*)d_in[3];
    const int*   dst      = (const int*)d_in[4];
    const float* W        = (const float*)d_in[5];
    const float* b        = (const float*)d_in[6];
    float* out = (float*)d_out;

    if (ws_size >= (size_t)WS_FULL) {
        char* w = (char*)d_ws;
        int*            cnt      = (int*)(w + 0);
        int*            offs     = (int*)(w + 401408);
        int*            partials = (int*)(w + 802816);
        int*            ssrc     = (int*)(w + 804864);
        unsigned short* h        = (unsigned short*)(w + 7204864);

        prep_h_kernel<<<(N_NODES * 32) / 256, 256, 0, stream>>>(feat, out_norm, h, cnt);
        hist_kernel<<<N_EDGES / 256, 256, 0, stream>>>(dst, cnt);
        scanA_kernel<<<NBLK, 256, 0, stream>>>(cnt, offs, partials);
        scanB_kernel<<<1, 512, 0, stream>>>(partials, NBLK);
        scanC_kernel<<<NBLK, 256, 0, stream>>>(offs, partials);
        fill_kernel<<<N_EDGES / 256, 256, 0, stream>>>(src, dst, offs, ssrc);
        gather_bf16_kernel<<<N_NODES / 4, 256, 0, stream>>>(h, offs, ssrc, out);
        transform_mfma_kernel<<<(N_NODES / 16 + 3) / 4, 256, 0, stream>>>(out, in_norm, W, b);
    } else if (ws_size >= (size_t)WS_R2) {
        char* w = (char*)d_ws;
        int*   cnt      = (int*)(w + 0);
        int*   offs     = (int*)(w + 401408);
        float* rno      = (float*)(w + 802816);
        int*   partials = (int*)(w + 1204224);
        int*   ssrc     = (int*)(w + 1206272);

        prep_kernel<<<NBLK, 256, 0, stream>>>(out_norm, rno, cnt);
        hist_kernel<<<N_EDGES / 256, 256, 0, stream>>>(dst, cnt);
        scanA_kernel<<<NBLK, 256, 0, stream>>>(cnt, offs, partials);
        scanB_kernel<<<1, 512, 0, stream>>>(partials, NBLK);
        scanC_kernel<<<NBLK, 256, 0, stream>>>(offs, partials);
        fill_kernel<<<N_EDGES / 256, 256, 0, stream>>>(src, dst, offs, ssrc);
        gather_kernel<<<N_NODES / 4, 256, 0, stream>>>(feat, rno, offs, ssrc, out);
        transform_kernel<<<2048, 256, 0, stream>>>(out, in_norm, W, b);
    } else {
        hipMemsetAsync(out, 0, (size_t)N_NODES * F * sizeof(float), stream);
        scatter_kernel<<<N_EDGES / 4, 256, 0, stream>>>(feat, out_norm, src, dst, out);
        transform_kernel<<<2048, 256, 0, stream>>>(out, in_norm, W, b);
    }
}

// Round 4
// 287.646 us; speedup vs baseline: 5.4295x; 1.3808x over previous
//
#include <hip/hip_runtime.h>

#define N_NODES 100000
#define N_EDGES 1600000
#define F 128
#define NB_C 196            // coarse buckets = ceil(N_NODES/512)
#define CHUNK 4000
#define NBLK_BIN 400        // 400 * 4000 = 1.6M exact
#define CAP 9984            // finesort LDS capacity (mean 8192, +20 sigma)

// ---------------- workspace layout (bytes) ----------------
// pool  : N_EDGES ints   @ 0          (6,400,000)  packed edges -> sorted src
// offs  : 100352 ints    @ 6400000    (401,408)    per-node END offsets
// base  : 400*196 ints   @ 6801408    (313,600)    per-(block,bucket) bases
// bbase : 256 ints       @ 7115008    (1,024)      coarse bucket bases
// h     : N*128 bf16     @ 7116032    (25,600,000) h = feat/out_norm
// total 32,716,032  (< 32,804,864 proven available in R3)
#define WS_V4 32716032

typedef __attribute__((ext_vector_type(8))) short short8;
typedef __attribute__((ext_vector_type(4))) float f32x4;

__device__ __forceinline__ unsigned short f2bf(float f) {
    unsigned u = __float_as_uint(f);
    return (unsigned short)((u + 0x7fffu + ((u >> 16) & 1u)) >> 16);
}

// ---------------------------------------------------------------------------
// prep: h[i][j] = bf16(feat[i][j] / out_norm[i]).  One thread per float4.
// ---------------------------------------------------------------------------
__global__ __launch_bounds__(256) void prep_h_kernel(
    const float* __restrict__ feat, const float* __restrict__ out_norm,
    unsigned short* __restrict__ h)
{
    int q = blockIdx.x * 256 + threadIdx.x;      // grid exact: N*32/256
    int row = q >> 5;
    float r = 1.0f / out_norm[row];
    float4 v = ((const float4*)feat)[q];
    ushort4 o;
    o.x = f2bf(v.x * r); o.y = f2bf(v.y * r);
    o.z = f2bf(v.z * r); o.w = f2bf(v.w * r);
    ((ushort4*)h)[q] = o;
}

// ---------------------------------------------------------------------------
// Phase 1: per-block LDS histogram over 196 coarse buckets (dst >> 9).
// ---------------------------------------------------------------------------
__global__ __launch_bounds__(256) void chist_kernel(
    const int* __restrict__ dst, int* __restrict__ base)
{
    __shared__ int c[NB_C];
    int t = threadIdx.x, blk = blockIdx.x;
    if (t < NB_C) c[t] = 0;
    __syncthreads();
    int e0 = blk * CHUNK;
    for (int i = t; i < CHUNK; i += 256)
        atomicAdd(&c[dst[e0 + i] >> 9], 1);
    __syncthreads();
    if (t < NB_C) base[blk * NB_C + t] = c[t];
}

// ---------------------------------------------------------------------------
// Phase 2 (1 block): column prefix over the 400x196 matrix + bucket-base scan.
// After this, base[blk][b] = absolute output position for that run's start.
// ---------------------------------------------------------------------------
__global__ __launch_bounds__(256) void cscan_kernel(
    int* __restrict__ base, int* __restrict__ bbase)
{
    __shared__ int sm[256];
    int t = threadIdx.x;
    int sum = 0;
    if (t < NB_C) {
        for (int blk = 0; blk < NBLK_BIN; ++blk) {
            int idx = blk * NB_C + t;
            int v = base[idx];
            base[idx] = sum;
            sum += v;
        }
    }
    sm[t] = (t < NB_C) ? sum : 0;
    __syncthreads();
    for (int off = 1; off < 256; off <<= 1) {
        int v = (t >= off) ? sm[t - off] : 0;
        __syncthreads();
        sm[t] += v;
        __syncthreads();
    }
    if (t < NB_C) {
        int excl = sm[t] - sum;
        bbase[t] = excl;
        for (int blk = 0; blk < NBLK_BIN; ++blk)
            base[blk * NB_C + t] += excl;
    }
    if (t == 0) bbase[NB_C] = N_EDGES;
}

// ---------------------------------------------------------------------------
// Phase 3: scatter packed edges ((dst&511)<<17 | src) into bucket-grouped
// pool. Same-(block,bucket) edges land contiguously (~80 B runs) -> writes
// stay line-dense instead of 16x write-amplified.
// ---------------------------------------------------------------------------
__global__ __launch_bounds__(256) void binscatter_kernel(
    const int* __restrict__ src, const int* __restrict__ dst,
    const int* __restrict__ base, int* __restrict__ pool)
{
    __shared__ int cba[NB_C];
    int t = threadIdx.x, blk = blockIdx.x;
    if (t < NB_C) cba[t] = base[blk * NB_C + t];
    __syncthreads();
    int e0 = blk * CHUNK;
    for (int i = t; i < CHUNK; i += 256) {
        int d = dst[e0 + i];
        int s = src[e0 + i];
        int b = d >> 9;
        int pos = atomicAdd(&cba[b], 1);
        pool[pos] = ((d & 511) << 17) | s;
    }
}

// ---------------------------------------------------------------------------
// Phase 4: per-bucket fine counting sort, fully LDS-staged. Writes sorted
// src ids back into pool in place and emits per-node END offsets.
// LDS: 9984*4 + 3*512*4 = 46 KB.
// ---------------------------------------------------------------------------
__global__ __launch_bounds__(1024) void finesort_kernel(
    int* __restrict__ pool, const int* __restrict__ bbase,
    int* __restrict__ offs)
{
    __shared__ int pairs[CAP];
    __shared__ int fcnt[512];
    __shared__ int s0[512];
    __shared__ int sexcl[512];
    int t = threadIdx.x, b = blockIdx.x;
    int beg = bbase[b];
    int end = bbase[b + 1];
    int cnt = end - beg;
    if (cnt > CAP) cnt = CAP;   // statistically unreachable (mean+20 sigma)
    for (int i = t; i < cnt; i += 1024) pairs[i] = pool[beg + i];
    if (t < 512) fcnt[t] = 0;
    __syncthreads();
    for (int i = t; i < cnt; i += 1024) atomicAdd(&fcnt[pairs[i] >> 17], 1);
    __syncthreads();
    if (t < 512) s0[t] = fcnt[t];
    __syncthreads();
    for (int off = 1; off < 512; off <<= 1) {
        int v = (t >= off && t < 512) ? s0[t - off] : 0;
        __syncthreads();
        if (t < 512) s0[t] += v;
        __syncthreads();
    }
    int node0 = b << 9;
    if (t < 512) {
        sexcl[t] = beg + s0[t] - fcnt[t];
        int node = node0 + t;
        if (node < N_NODES) offs[node] = beg + s0[t];   // inclusive END
    }
    __syncthreads();
    for (int i = t; i < cnt; i += 1024) {
        int p = pairs[i];
        int pos = atomicAdd(&sexcl[p >> 17], 1);
        pool[pos] = p & 0x1FFFF;                        // sorted src id
    }
}

// ---------------------------------------------------------------------------
// Gather: one wave per node; lane reads one uint (2 bf16) per incident row.
// 1/in_norm folded in here; agg (fp32) written exactly once, no atomics.
// ---------------------------------------------------------------------------
__global__ __launch_bounds__(256) void gather_bf16_kernel(
    const unsigned short* __restrict__ h, const int* __restrict__ offs,
    const int* __restrict__ ssrc, const float* __restrict__ in_norm,
    float* __restrict__ agg)
{
    const int wave = threadIdx.x >> 6, lane = threadIdx.x & 63;
    const int i = blockIdx.x * 4 + wave;      // grid = N/4 exact
    const int start = (i == 0) ? 0 : offs[i - 1];
    const int end = offs[i];
    const unsigned* hp = (const unsigned*)h;
    float ax = 0.f, ay = 0.f;
    int e = start;
    for (; e + 3 < end; e += 4) {
        unsigned u0 = hp[(size_t)ssrc[e]     * 64 + lane];
        unsigned u1 = hp[(size_t)ssrc[e + 1] * 64 + lane];
        unsigned u2 = hp[(size_t)ssrc[e + 2] * 64 + lane];
        unsigned u3 = hp[(size_t)ssrc[e + 3] * 64 + lane];
        ax += __uint_as_float(u0 << 16) + __uint_as_float(u1 << 16)
            + __uint_as_float(u2 << 16) + __uint_as_float(u3 << 16);
        ay += __uint_as_float(u0 & 0xffff0000u) + __uint_as_float(u1 & 0xffff0000u)
            + __uint_as_float(u2 & 0xffff0000u) + __uint_as_float(u3 & 0xffff0000u);
    }
    for (; e < end; ++e) {
        unsigned u = hp[(size_t)ssrc[e] * 64 + lane];
        ax += __uint_as_float(u << 16);
        ay += __uint_as_float(u & 0xffff0000u);
    }
    const float rin = 1.0f / in_norm[i];
    float2 o; o.x = ax * rin; o.y = ay * rin;
    ((float2*)agg)[(size_t)i * 64 + lane] = o;
}

// ---------------------------------------------------------------------------
// MFMA transform (in-place on d_out): out = agg @ W^T + b.
// rin already applied by gather. Same verified structure as R3.
// ---------------------------------------------------------------------------
__global__ __launch_bounds__(256) void transform_mfma_kernel(
    float* __restrict__ out, const float* __restrict__ W,
    const float* __restrict__ bias)
{
    __shared__ short Wb[F * F];   // 32 KB bf16, chunk-XOR swizzled
    const int t = threadIdx.x;
    #pragma unroll
    for (int i = 0; i < 8; ++i) {
        int c = t + i * 256;
        int n = c >> 4, kc = c & 15;
        const float4* wp = (const float4*)(W + n * F + kc * 8);
        float4 w0 = wp[0], w1 = wp[1];
        short8 v;
        v[0] = (short)f2bf(w0.x); v[1] = (short)f2bf(w0.y);
        v[2] = (short)f2bf(w0.z); v[3] = (short)f2bf(w0.w);
        v[4] = (short)f2bf(w1.x); v[5] = (short)f2bf(w1.y);
        v[6] = (short)f2bf(w1.z); v[7] = (short)f2bf(w1.w);
        *(short8*)&Wb[n * F + ((kc ^ (n & 15)) * 8)] = v;
    }
    __syncthreads();

    const int wave = t >> 6, lane = t & 63;
    const int wblk = blockIdx.x * 4 + wave;
    if (wblk >= N_NODES / 16) return;
    const int r0 = wblk * 16;
    const int m = lane & 15, q = lane >> 4;
    const float4* arow = (const float4*)(out + (size_t)(r0 + m) * F);

    short8 afrag[4];
    #pragma unroll
    for (int s = 0; s < 4; ++s) {
        int k0 = s * 32 + q * 8;
        float4 x0 = arow[k0 >> 2];
        float4 x1 = arow[(k0 >> 2) + 1];
        short8 a;
        a[0] = (short)f2bf(x0.x); a[1] = (short)f2bf(x0.y);
        a[2] = (short)f2bf(x0.z); a[3] = (short)f2bf(x0.w);
        a[4] = (short)f2bf(x1.x); a[5] = (short)f2bf(x1.y);
        a[6] = (short)f2bf(x1.z); a[7] = (short)f2bf(x1.w);
        afrag[s] = a;
    }

    f32x4 acc[8];
    #pragma unroll
    for (int c = 0; c < 8; ++c) { f32x4 z = {0.f, 0.f, 0.f, 0.f}; acc[c] = z; }

    #pragma unroll
    for (int s = 0; s < 4; ++s) {
        const int kc = s * 4 + q;
        #pragma unroll
        for (int c = 0; c < 8; ++c) {
            const int n = c * 16 + m;
            short8 bfrag = *(const short8*)&Wb[n * F + ((kc ^ m) * 8)];
            acc[c] = __builtin_amdgcn_mfma_f32_16x16x32_bf16(
                afrag[s], bfrag, acc[c], 0, 0, 0);
        }
    }

    #pragma unroll
    for (int c = 0; c < 8; ++c) {
        const float bc = bias[c * 16 + m];
        #pragma unroll
        for (int r = 0; r < 4; ++r) {
            out[(size_t)(r0 + q * 4 + r) * F + c * 16 + m] = acc[c][r] + bc;
        }
    }
}

// ---------------------------------------------------------------------------
// Parachute fallback (tiny ws): R1 atomic scatter + fp32 VALU transform.
// ---------------------------------------------------------------------------
__global__ __launch_bounds__(256) void scatter_kernel(
    const float* __restrict__ feat, const float* __restrict__ out_norm,
    const int* __restrict__ src, const int* __restrict__ dst,
    float* __restrict__ agg)
{
    const int wave = threadIdx.x >> 6;
    const int lane = threadIdx.x & 63;
    const int e = blockIdx.x * 4 + wave;
    const int s = src[e];
    const int d = dst[e];
    const float rn = 1.0f / out_norm[s];
    const float2 v = ((const float2*)(feat + (size_t)s * F))[lane];
    float* ap = agg + (size_t)d * F + lane * 2;
    unsafeAtomicAdd(ap,     v.x * rn);
    unsafeAtomicAdd(ap + 1, v.y * rn);
}

__global__ __launch_bounds__(256) void transform_kernel(
    float* __restrict__ out, const float* __restrict__ in_norm,
    const float* __restrict__ W, const float* __restrict__ bias)
{
    __shared__ float Wt[F * F];
    const int t = threadIdx.x;
    #pragma unroll
    for (int i = 0; i < (F * F) / 256; ++i) {
        int idx = t + i * 256;
        int j = idx >> 7;
        int k = idx & (F - 1);
        Wt[k * F + j] = W[idx];
    }
    __syncthreads();
    const int wave = t >> 6, lane = t & 63;
    const float b0 = bias[lane];
    const float b1 = bias[lane + 64];
    const int ngroups = N_NODES / 16;
    for (int g = blockIdx.x; g < ngroups; g += gridDim.x) {
        const int r = g * 16 + wave * 4;
        const float4* a0 = (const float4*)(out + (size_t)r * F);
        const float4* a1 = a0 + F / 4;
        const float4* a2 = a0 + 2 * (F / 4);
        const float4* a3 = a0 + 3 * (F / 4);
        float acc00 = 0.f, acc01 = 0.f, acc10 = 0.f, acc11 = 0.f;
        float acc20 = 0.f, acc21 = 0.f, acc30 = 0.f, acc31 = 0.f;
        for (int k4 = 0; k4 < F / 4; ++k4) {
            const float4 x0 = a0[k4]; const float4 x1 = a1[k4];
            const float4 x2 = a2[k4]; const float4 x3 = a3[k4];
            const float xs0[4] = {x0.x, x0.y, x0.z, x0.w};
            const float xs1[4] = {x1.x, x1.y, x1.z, x1.w};
            const float xs2[4] = {x2.x, x2.y, x2.z, x2.w};
            const float xs3[4] = {x3.x, x3.y, x3.z, x3.w};
            #pragma unroll
            for (int kk = 0; kk < 4; ++kk) {
                const int k = k4 * 4 + kk;
                const float w0 = Wt[k * F + lane];
                const float w1 = Wt[k * F + 64 + lane];
                acc00 = fmaf(xs0[kk], w0, acc00); acc01 = fmaf(xs0[kk], w1, acc01);
                acc10 = fmaf(xs1[kk], w0, acc10); acc11 = fmaf(xs1[kk], w1, acc11);
                acc20 = fmaf(xs2[kk], w0, acc20); acc21 = fmaf(xs2[kk], w1, acc21);
                acc30 = fmaf(xs3[kk], w0, acc30); acc31 = fmaf(xs3[kk], w1, acc31);
            }
        }
        const float i0 = 1.0f / in_norm[r + 0];
        const float i1 = 1.0f / in_norm[r + 1];
        const float i2 = 1.0f / in_norm[r + 2];
        const float i3 = 1.0f / in_norm[r + 3];
        out[(size_t)(r + 0) * F + lane]      = acc00 * i0 + b0;
        out[(size_t)(r + 0) * F + 64 + lane] = acc01 * i0 + b1;
        out[(size_t)(r + 1) * F + lane]      = acc10 * i1 + b0;
        out[(size_t)(r + 1) * F + 64 + lane] = acc11 * i1 + b1;
        out[(size_t)(r + 2) * F + lane]      = acc20 * i2 + b0;
        out[(size_t)(r + 2) * F + 64 + lane] = acc21 * i2 + b1;
        out[(size_t)(r + 3) * F + lane]      = acc30 * i3 + b0;
        out[(size_t)(r + 3) * F + 64 + lane] = acc31 * i3 + b1;
    }
}

extern "C" void kernel_launch(void* const* d_in, const int* in_sizes, int n_in,
                              void* d_out, int out_size, void* d_ws, size_t ws_size,
                              hipStream_t stream) {
    const float* feat     = (const float*)d_in[0];
    const float* in_norm  = (const float*)d_in[1];
    const float* out_norm = (const float*)d_in[2];
    const int*   src      = (const int*)d_in[3];
    const int*   dst      = (const int*)d_in[4];
    const float* W        = (const float*)d_in[5];
    const float* b        = (const float*)d_in[6];
    float* out = (float*)d_out;

    if (ws_size >= (size_t)WS_V4) {
        char* w = (char*)d_ws;
        int*            pool  = (int*)(w + 0);
        int*            offs  = (int*)(w + 6400000);
        int*            base  = (int*)(w + 6801408);
        int*            bbase = (int*)(w + 7115008);
        unsigned short* h     = (unsigned short*)(w + 7116032);

        prep_h_kernel<<<(N_NODES * 32) / 256, 256, 0, stream>>>(feat, out_norm, h);
        chist_kernel<<<NBLK_BIN, 256, 0, stream>>>(dst, base);
        cscan_kernel<<<1, 256, 0, stream>>>(base, bbase);
        binscatter_kernel<<<NBLK_BIN, 256, 0, stream>>>(src, dst, base, pool);
        finesort_kernel<<<NB_C, 1024, 0, stream>>>(pool, bbase, offs);
        gather_bf16_kernel<<<N_NODES / 4, 256, 0, stream>>>(h, offs, pool, in_norm, out);
        transform_mfma_kernel<<<(N_NODES / 16 + 3) / 4, 256, 0, stream>>>(out, W, b);
    } else {
        hipMemsetAsync(out, 0, (size_t)N_NODES * F * sizeof(float), stream);
        scatter_kernel<<<N_EDGES / 4, 256, 0, stream>>>(feat, out_norm, src, dst, out);
        transform_kernel<<<2048, 256, 0, stream>>>(out, in_norm, W, b);
    }
}